// Round 5
// baseline (171.668 us; speedup 1.0000x reference)
//
#include <hip/hip_runtime.h>
#include <cstddef>
#include <cstdint>

#define BB 8
#define SS 256
#define EE 256
#define NN1 16
#define NN2 16
#define DD 100
#define QQ 768

__device__ __forceinline__ float dot4(float4 a, float4 b) {
    return a.x * b.x + a.y * b.y + a.z * b.z + a.w * b.w;
}

// ---------------------------------------------------------------------------
// prep: blocks 0..15 -> per (b, layer) compute qk = 0.1 * Wk^T tanh(Wq q0 + bq)
//       blocks 16..23 -> per b inclusive scan of (input_ent != 0) -> rank (-1 = masked)
// ---------------------------------------------------------------------------
__global__ __launch_bounds__(256) void prep_kernel(
    const float* __restrict__ q, const int* __restrict__ ent,
    const float* __restrict__ Wq2, const float* __restrict__ bq2, const float* __restrict__ Wk2,
    const float* __restrict__ Wq1, const float* __restrict__ bq1, const float* __restrict__ Wk1,
    float* __restrict__ qk2o, float* __restrict__ qk1o, int* __restrict__ rk)
{
    const int blk = blockIdx.x, t = threadIdx.x;
    if (blk < 16) {
        const int b = blk >> 1, layer = blk & 1;
        const float* Wq = layer ? Wq1 : Wq2;
        const float* bq = layer ? bq1 : bq2;
        const float* Wk = layer ? Wk1 : Wk2;
        float* qko      = layer ? qk1o : qk2o;
        __shared__ float s_q[QQ];
        __shared__ float s_qi[DD];
        for (int i = t; i < QQ; i += 256) s_q[i] = q[(size_t)b * SS * QQ + i]; // q[b,0,:]
        __syncthreads();
        const float4* sq4 = (const float4*)s_q;
        const int r = t & 7;
        for (int d = t >> 3; d < DD; d += 32) {
            const float4* wq4 = (const float4*)(Wq + (size_t)d * QQ);
            float acc = 0.f;
            for (int c = r; c < QQ / 4; c += 8) acc += dot4(wq4[c], sq4[c]);
            acc += __shfl_xor(acc, 1, 8);
            acc += __shfl_xor(acc, 2, 8);
            acc += __shfl_xor(acc, 4, 8);
            if (r == 0) s_qi[d] = tanhf(acc + bq[d]);
        }
        __syncthreads();
        if (t < DD) {
            float acc = 0.f;
            for (int d = 0; d < DD; ++d) acc += s_qi[d] * Wk[d * DD + t]; // (Wk^T q_i)[t]
            qko[b * DD + t] = 0.1f * acc;   // fold 1/sqrt(100)
        }
    } else {
        const int b = blk - 16;
        __shared__ int s_m[SS];
        const int m = (ent[b * SS + t] != 0) ? 1 : 0;
        s_m[t] = m;
        __syncthreads();
        for (int off = 1; off < SS; off <<= 1) {
            const int add = (t >= off) ? s_m[t - off] : 0;
            __syncthreads();
            s_m[t] += add;
            __syncthreads();
        }
        int rank = s_m[t] - 1;
        rank = rank < 0 ? 0 : (rank > EE - 1 ? EE - 1 : rank);
        rk[b * SS + t] = m ? rank : -1;
    }
}

// ---------------------------------------------------------------------------
// dk2: persistent grid-stride. Unit = pair of n1-tiles (800 float4 of k2/v2).
// K for unit i+1 prefetched into regs while unit i computes; V global->reg->
// p*v partials in LDS -> transpose-sum. Loads outstanding ~100% of lifetime.
// ---------------------------------------------------------------------------
__global__ __launch_bounds__(256, 8) void dk2_kernel(
    const float* __restrict__ k2, const float* __restrict__ v2,
    const float* __restrict__ qk2g, float* __restrict__ c2o,
    int b0, int nb, int nunits)
{
    const int t = threadIdx.x;
    __shared__ float  s_part[800];
    __shared__ float4 s_pp[800];
    __shared__ float  s_q[800];          // qk for up to 8 b's
    __shared__ float  s_logit[32];
    __shared__ float  s_p[32];

    for (int i = t; i < nb * DD; i += 256) s_q[i] = qk2g[b0 * DD + i];
    const float4* sq4 = (const float4*)s_q;

    const int i0 = t, i1 = t + 256, i2 = t + 512, i3 = t + 768;
    const int c0 = i0 % 25, c1 = i1 % 25, c2x = i2 % 25, c3 = i3 % 25;
    const int n0 = i0 / 25, n1_ = i1 / 25, n2_ = i2 / 25, n3_ = i3 / 25;  // pair-row 0..31

    int u = blockIdx.x;
    float4 ka0, ka1, ka2, ka3;
    if (u < nunits) {   // prologue: issue K for first unit
        const int pi  = u & 7;
        const int bbe = u >> 3;
        const int be  = ((b0 + (bbe >> 8)) << 8) | (bbe & 255);
        const float4* kt = (const float4*)k2 + ((size_t)(be * NN1 + pi * 2)) * 400;
        ka0 = kt[i0]; ka1 = kt[i1]; ka2 = kt[i2];
        if (t < 32) ka3 = kt[i3];
    }
    __syncthreads();     // s_q ready

    while (u < nunits) {
        const int pi   = u & 7;
        const int bbe  = u >> 3;
        const int brel = bbe >> 8;
        const int be   = ((b0 + brel) << 8) | (bbe & 255);
        const size_t tb = ((size_t)(be * NN1 + pi * 2)) * 400;

        // stage dot partials (waits on ka regs)
        const int qb = brel * 25;
        s_part[i0] = dot4(ka0, sq4[qb + c0]);
        s_part[i1] = dot4(ka1, sq4[qb + c1]);
        s_part[i2] = dot4(ka2, sq4[qb + c2x]);
        if (t < 32) s_part[i3] = dot4(ka3, sq4[qb + c3]);

        // issue V for this unit
        const float4* vt = (const float4*)v2 + tb;
        float4 va0 = vt[i0], va1 = vt[i1], va2 = vt[i2], va3;
        if (t < 32) va3 = vt[i3];

        // issue K for next unit
        const int un = u + gridDim.x;
        if (un < nunits) {
            const int pin  = un & 7;
            const int bben = un >> 3;
            const int ben  = ((b0 + (bben >> 8)) << 8) | (bben & 255);
            const float4* ktn = (const float4*)k2 + ((size_t)(ben * NN1 + pin * 2)) * 400;
            ka0 = ktn[i0]; ka1 = ktn[i1]; ka2 = ktn[i2];
            if (t < 32) ka3 = ktn[i3];
        }

        __syncthreads();   // B: s_part ready
        if (t < 32) {      // row sums; stride 25 coprime 32 -> conflict-free
            float acc = 0.f;
            #pragma unroll
            for (int c = 0; c < 25; ++c) acc += s_part[t * 25 + c];
            if (acc == 0.0f) acc = -10000.0f;
            s_logit[t] = acc >= 0.f ? acc : 0.01f * acc;   // leaky_relu
        }
        __syncthreads();   // C
        if (t < 32) {      // softmax per 16-row half (lanes 0-15, 16-31)
            const float lg = s_logit[t];
            float mx = lg;
            mx = fmaxf(mx, __shfl_xor(mx, 1, 16));
            mx = fmaxf(mx, __shfl_xor(mx, 2, 16));
            mx = fmaxf(mx, __shfl_xor(mx, 4, 16));
            mx = fmaxf(mx, __shfl_xor(mx, 8, 16));
            const float e = __expf(lg - mx);
            float sm = e;
            sm += __shfl_xor(sm, 1, 16);
            sm += __shfl_xor(sm, 2, 16);
            sm += __shfl_xor(sm, 4, 16);
            sm += __shfl_xor(sm, 8, 16);
            float p = e / sm;
            if (p == 0.0625f) p = 0.f;     // where(attn == 1/n, 0)
            s_p[t] = p;
        }
        __syncthreads();   // D: s_p ready
        {                  // p * v partials (waits on va regs)
            float p;
            p = s_p[n0]; s_pp[i0] = make_float4(p*va0.x, p*va0.y, p*va0.z, p*va0.w);
            p = s_p[n1_]; s_pp[i1] = make_float4(p*va1.x, p*va1.y, p*va1.z, p*va1.w);
            p = s_p[n2_]; s_pp[i2] = make_float4(p*va2.x, p*va2.y, p*va2.z, p*va2.w);
            if (t < 32) { p = s_p[n3_]; s_pp[i3] = make_float4(p*va3.x, p*va3.y, p*va3.z, p*va3.w); }
        }
        __syncthreads();   // E: s_pp ready
        if (t < 50) {      // transpose-sum: out[h][c] = sum_n s_pp[h*400+n*25+c]
            const int h = t / 25, c = t % 25;
            float4 a = make_float4(0.f, 0.f, 0.f, 0.f);
            #pragma unroll
            for (int n = 0; n < 16; ++n) {
                const float4 x = s_pp[h * 400 + n * 25 + c];
                a.x += x.x; a.y += x.y; a.z += x.z; a.w += x.w;
            }
            ((float4*)c2o)[((size_t)bbe * NN1 + pi * 2 + h) * 25 + c] = a;
        }
        u = un;
        // no trailing barrier needed: next-iter s_part writes don't touch s_pp,
        // and barrier B gates next s_logit/s_p/s_pp writes behind out-phase.
    }
}

// ---------------------------------------------------------------------------
// dk1: one block per (bb,e). k1/v1/c2 all float4-staged, issued up front.
// ---------------------------------------------------------------------------
__global__ __launch_bounds__(256) void dk1_kernel(
    const float* __restrict__ k1, const float* __restrict__ v1,
    const float* __restrict__ c2i, const float* __restrict__ qk1g,
    float* __restrict__ comb, int b0)
{
    const int bbe = blockIdx.x;          // bb*256 + e
    const int b   = b0 + (bbe >> 8);
    const int be  = (b << 8) | (bbe & 255);
    const int t   = threadIdx.x;

    __shared__ float s_part[400];
    __shared__ float s_v[1600];
    __shared__ float s_c[1600];
    __shared__ float s_logit[16];
    float4* sv4 = (float4*)s_v;
    float4* sc4 = (float4*)s_c;

    const float4* kt  = (const float4*)k1 + (size_t)be * 400;
    const float4* vt  = (const float4*)v1 + (size_t)be * 400;
    const float4* ct  = (const float4*)c2i + (size_t)bbe * 400;
    const float4* qkb = (const float4*)qk1g + b * 25;

    const int i0 = t, i1 = t + 256;
    float4 ka0 = kt[i0], va0 = vt[i0], ca0 = ct[i0];
    float4 ka1, va1, ca1;
    if (t < 144) { ka1 = kt[i1]; va1 = vt[i1]; ca1 = ct[i1]; }
    const int c0 = i0 % 25, c1 = i1 % 25;
    const float4 q0 = qkb[c0], q1 = qkb[c1];

    s_part[i0] = dot4(ka0, q0); sv4[i0] = va0; sc4[i0] = ca0;
    if (t < 144) { s_part[i1] = dot4(ka1, q1); sv4[i1] = va1; sc4[i1] = ca1; }
    __syncthreads();

    if (t < 16) {
        float acc = 0.f;
        #pragma unroll
        for (int c = 0; c < 25; ++c) acc += s_part[t * 25 + c];
        if (acc == 0.0f) acc = -10000.0f;
        s_logit[t] = acc >= 0.f ? acc : 0.01f * acc;
    }
    __syncthreads();

    float lg = s_logit[t & 15];
    float mx = lg;
    mx = fmaxf(mx, __shfl_xor(mx, 1, 16));
    mx = fmaxf(mx, __shfl_xor(mx, 2, 16));
    mx = fmaxf(mx, __shfl_xor(mx, 4, 16));
    mx = fmaxf(mx, __shfl_xor(mx, 8, 16));
    const float e = __expf(lg - mx);
    float sm = e;
    sm += __shfl_xor(sm, 1, 16);
    sm += __shfl_xor(sm, 2, 16);
    sm += __shfl_xor(sm, 4, 16);
    sm += __shfl_xor(sm, 8, 16);
    float p = e / sm;
    if (p == 0.0625f) p = 0.f;
    float pn[16];
    #pragma unroll
    for (int n = 0; n < 16; ++n) pn[n] = __shfl(p, n, 16);

    if (t < 2 * DD) {
        float a = 0.f;
        if (t < DD) {
            #pragma unroll
            for (int n = 0; n < NN1; ++n) a += pn[n] * s_v[n * DD + t];
        } else {
            const int d = t - DD;
            #pragma unroll
            for (int n = 0; n < NN1; ++n) a += pn[n] * s_c[n * DD + d];
        }
        comb[(size_t)be * (2 * DD) + t] = a;
    }
}

// ---------------------------------------------------------------------------
// gather: one block per (b,s)
// ---------------------------------------------------------------------------
__global__ __launch_bounds__(64) void gather_kernel(
    const float* __restrict__ comb, const int* __restrict__ rk, float* __restrict__ out)
{
    const int bs = blockIdx.x;
    const int b  = bs >> 8;
    const int t  = threadIdx.x;
    const int r  = rk[bs];
    float* o = out + (size_t)bs * (2 * DD);
    if (r < 0) {
        for (int d = t; d < 2 * DD; d += 64) o[d] = 0.f;
    } else {
        const float* src = comb + (size_t)(b * EE + r) * (2 * DD);
        for (int d = t; d < 2 * DD; d += 64) o[d] = src[d];
    }
}

extern "C" void kernel_launch(void* const* d_in, const int* in_sizes, int n_in,
                              void* d_out, int out_size, void* d_ws, size_t ws_size,
                              hipStream_t stream)
{
    const int*   ent = (const int*)d_in[0];
    const float* q   = (const float*)d_in[1];
    const float* k1  = (const float*)d_in[2];
    const float* v1  = (const float*)d_in[3];
    const float* k2  = (const float*)d_in[4];
    const float* v2  = (const float*)d_in[5];
    const float* Wq2 = (const float*)d_in[6];
    const float* bq2 = (const float*)d_in[7];
    const float* Wk2 = (const float*)d_in[8];
    const float* Wq1 = (const float*)d_in[9];
    const float* bq1 = (const float*)d_in[10];
    const float* Wk1 = (const float*)d_in[11];
    float* out = (float*)d_out;

    float* ws   = (float*)d_ws;
    float* qk2  = ws;                          // [0, 1024)
    float* qk1  = ws + 1024;                   // [1024, 2048)
    int*   rk   = (int*)(ws + 2048);           // [2048, 4096) as ints
    float* comb = ws + 4096;                   // [4096, 4096+409600)
    float* c2   = ws + 4096 + 409600;          // per-b chunks of 409600 floats

    const size_t fixed = 4096 + 409600;        // floats
    const size_t perb  = (size_t)EE * NN1 * DD; // 409600 floats per batch
    size_t wsf = ws_size / sizeof(float);
    int kb = (wsf > fixed) ? (int)((wsf - fixed) / perb) : 1;
    if (kb < 1) kb = 1;
    if (kb > BB) kb = BB;

    prep_kernel<<<24, 256, 0, stream>>>(q, ent, Wq2, bq2, Wk2, Wq1, bq1, Wk1, qk2, qk1, rk);
    for (int b0 = 0; b0 < BB; b0 += kb) {
        const int nb = (BB - b0 < kb) ? (BB - b0) : kb;
        const int nunits = nb * EE * 8;        // pair-units
        const int grid = nunits < 2048 ? nunits : 2048;
        dk2_kernel<<<grid, 256, 0, stream>>>(k2, v2, qk2, c2, b0, nb, nunits);
        dk1_kernel<<<nb * EE, 256, 0, stream>>>(k1, v1, c2, qk1, comb, b0);
    }
    gather_kernel<<<BB * SS, 64, 0, stream>>>(comb, rk, out);
}

// Round 6
// 155.013 us; speedup vs baseline: 1.1074x; 1.1074x over previous
//
#include <hip/hip_runtime.h>
#include <cstddef>
#include <cstdint>

#define BB 8
#define SS 256
#define EE 256
#define NN1 16
#define NN2 16
#define DD 100
#define QQ 768

__device__ __forceinline__ float dot4(float4 a, float4 b) {
    return a.x * b.x + a.y * b.y + a.z * b.z + a.w * b.w;
}

// ---------------------------------------------------------------------------
// prep: blocks 0..15 -> per (b, layer) compute qk = 0.1 * Wk^T tanh(Wq q0 + bq)
//       blocks 16..23 -> per b inclusive scan of (input_ent != 0) -> rank (-1 = masked)
// ---------------------------------------------------------------------------
__global__ __launch_bounds__(256) void prep_kernel(
    const float* __restrict__ q, const int* __restrict__ ent,
    const float* __restrict__ Wq2, const float* __restrict__ bq2, const float* __restrict__ Wk2,
    const float* __restrict__ Wq1, const float* __restrict__ bq1, const float* __restrict__ Wk1,
    float* __restrict__ qk2o, float* __restrict__ qk1o, int* __restrict__ rk)
{
    const int blk = blockIdx.x, t = threadIdx.x;
    if (blk < 16) {
        const int b = blk >> 1, layer = blk & 1;
        const float* Wq = layer ? Wq1 : Wq2;
        const float* bq = layer ? bq1 : bq2;
        const float* Wk = layer ? Wk1 : Wk2;
        float* qko      = layer ? qk1o : qk2o;
        __shared__ float s_q[QQ];
        __shared__ float s_qi[DD];
        for (int i = t; i < QQ; i += 256) s_q[i] = q[(size_t)b * SS * QQ + i]; // q[b,0,:]
        __syncthreads();
        const float4* sq4 = (const float4*)s_q;
        const int r = t & 7;
        for (int d = t >> 3; d < DD; d += 32) {
            const float4* wq4 = (const float4*)(Wq + (size_t)d * QQ);
            float acc = 0.f;
            for (int c = r; c < QQ / 4; c += 8) acc += dot4(wq4[c], sq4[c]);
            acc += __shfl_xor(acc, 1, 8);
            acc += __shfl_xor(acc, 2, 8);
            acc += __shfl_xor(acc, 4, 8);
            if (r == 0) s_qi[d] = tanhf(acc + bq[d]);
        }
        __syncthreads();
        if (t < DD) {
            float acc = 0.f;
            for (int d = 0; d < DD; ++d) acc += s_qi[d] * Wk[d * DD + t]; // (Wk^T q_i)[t]
            qko[b * DD + t] = 0.1f * acc;   // fold 1/sqrt(100)
        }
    } else {
        const int b = blk - 16;
        __shared__ int s_m[SS];
        const int m = (ent[b * SS + t] != 0) ? 1 : 0;
        s_m[t] = m;
        __syncthreads();
        for (int off = 1; off < SS; off <<= 1) {
            const int add = (t >= off) ? s_m[t - off] : 0;
            __syncthreads();
            s_m[t] += add;
            __syncthreads();
        }
        int rank = s_m[t] - 1;
        rank = rank < 0 ? 0 : (rank > EE - 1 ? EE - 1 : rank);
        rk[b * SS + t] = m ? rank : -1;
    }
}

// ---------------------------------------------------------------------------
// dk2: SINGLE-WAVE blocks (64 thr). Unit = one n1 tile (16x100). Persistent
// grid-stride with next-K register prefetch; V issued before LDS consumption.
// __syncthreads in a 1-wave workgroup is just the required waitcnt -> no
// inter-wave coupling anywhere; loads stay in flight ~continuously.
// ---------------------------------------------------------------------------
__global__ __launch_bounds__(64) void dk2_kernel(
    const float* __restrict__ k2, const float* __restrict__ v2,
    const float* __restrict__ qk2g, float* __restrict__ c2o,
    int b0, int nunits)
{
    const int t = threadIdx.x;
    __shared__ float4 s_pp[400];               // 6.4 KB; also viewed as 1600 floats
    float* s_part = (float*)s_pp;              // part uses first 400 floats

    int u = blockIdx.x;
    const int stride = gridDim.x;
    const size_t gofs = (size_t)b0 * 4096;     // global tile offset for this chunk

    float4 ka[7];
    if (u < nunits) {
        const float4* kt = (const float4*)k2 + (gofs + u) * 400;
        #pragma unroll
        for (int j = 0; j < 6; ++j) ka[j] = kt[t + 64 * j];
        if (t < 16) ka[6] = kt[384 + t];
    }

    while (u < nunits) {
        const int b = b0 + (u >> 12);
        const float4* qk = (const float4*)qk2g + b * 25;
        const float4* vt = (const float4*)v2 + (gofs + u) * 400;

        // issue V for this unit up front
        float4 va[7];
        #pragma unroll
        for (int j = 0; j < 6; ++j) va[j] = vt[t + 64 * j];
        if (t < 16) va[6] = vt[384 + t];

        // dot partials into LDS (consumes ka)
        #pragma unroll
        for (int j = 0; j < 6; ++j) {
            const int i = t + 64 * j;
            s_part[i] = dot4(ka[j], qk[i % 25]);
        }
        if (t < 16) { const int i = 384 + t; s_part[i] = dot4(ka[6], qk[i % 25]); }

        // prefetch next unit's K
        const int un = u + stride;
        if (un < nunits) {
            const float4* ktn = (const float4*)k2 + (gofs + un) * 400;
            #pragma unroll
            for (int j = 0; j < 6; ++j) ka[j] = ktn[t + 64 * j];
            if (t < 16) ka[6] = ktn[384 + t];
        }

        __syncthreads();                       // part visible (1-wave: waitcnt only)
        float p = 0.f;
        {
            float lg = 0.f;
            if (t < 16) {
                #pragma unroll
                for (int c = 0; c < 25; ++c) lg += s_part[t * 25 + c];  // 25 coprime 32
                if (lg == 0.0f) lg = -10000.0f;
                lg = lg >= 0.f ? lg : 0.01f * lg;   // leaky_relu
            }
            float mx = lg;
            mx = fmaxf(mx, __shfl_xor(mx, 1, 16));
            mx = fmaxf(mx, __shfl_xor(mx, 2, 16));
            mx = fmaxf(mx, __shfl_xor(mx, 4, 16));
            mx = fmaxf(mx, __shfl_xor(mx, 8, 16));
            const float e = __expf(lg - mx);
            float sm = e;
            sm += __shfl_xor(sm, 1, 16);
            sm += __shfl_xor(sm, 2, 16);
            sm += __shfl_xor(sm, 4, 16);
            sm += __shfl_xor(sm, 8, 16);
            p = e / sm;
            if (p == 0.0625f) p = 0.f;         // where(attn == 1/n, 0)
        }
        __syncthreads();                       // part reads done before pp overwrite

        // pp = p[n] * v
        #pragma unroll
        for (int j = 0; j < 6; ++j) {
            const int i = t + 64 * j;
            const float pn = __shfl(p, i / 25, 64);
            s_pp[i] = make_float4(pn * va[j].x, pn * va[j].y, pn * va[j].z, pn * va[j].w);
        }
        if (t < 16) {
            const int i = 384 + t;
            const float pn = __shfl(p, 15, 64);
            s_pp[i] = make_float4(pn * va[6].x, pn * va[6].y, pn * va[6].z, pn * va[6].w);
        }
        __syncthreads();                       // pp visible

        if (t < 25) {                          // col sums -> 400 B contiguous store
            float4 a = make_float4(0.f, 0.f, 0.f, 0.f);
            #pragma unroll
            for (int n = 0; n < 16; ++n) {
                const float4 x = s_pp[n * 25 + t];
                a.x += x.x; a.y += x.y; a.z += x.z; a.w += x.w;
            }
            ((float4*)c2o)[(size_t)u * 25 + t] = a;   // chunk-local layout
        }
        __syncthreads();                       // pp reads done before next part writes
        u = un;
    }
}

// ---------------------------------------------------------------------------
// dk1: single-wave blocks, 2 per (bb,e): half 0 emits v1 part (d 0..99),
// half 1 emits c2 part (d 100..199). Both redundantly compute p (k1 hot in L1).
// ---------------------------------------------------------------------------
__global__ __launch_bounds__(64) void dk1_kernel(
    const float* __restrict__ k1, const float* __restrict__ v1,
    const float* __restrict__ c2i, const float* __restrict__ qk1g,
    float* __restrict__ comb, int b0)
{
    const int blk  = blockIdx.x;
    const int bbe  = blk >> 1;           // chunk-local (bb,e)
    const int half = blk & 1;
    const int b    = b0 + (bbe >> 8);
    const int be   = (b << 8) | (bbe & 255);
    const int t    = threadIdx.x;

    __shared__ float4 s_pp[400];
    float* s_part = (float*)s_pp;

    const float4* kt = (const float4*)k1 + (size_t)be * 400;
    const float4* vt = half ? (const float4*)c2i + (size_t)bbe * 400
                            : (const float4*)v1 + (size_t)be * 400;
    const float4* qk = (const float4*)qk1g + b * 25;

    float4 ka[7], va[7];
    #pragma unroll
    for (int j = 0; j < 6; ++j) { ka[j] = kt[t + 64 * j]; va[j] = vt[t + 64 * j]; }
    if (t < 16) { ka[6] = kt[384 + t]; va[6] = vt[384 + t]; }

    #pragma unroll
    for (int j = 0; j < 6; ++j) {
        const int i = t + 64 * j;
        s_part[i] = dot4(ka[j], qk[i % 25]);
    }
    if (t < 16) { const int i = 384 + t; s_part[i] = dot4(ka[6], qk[i % 25]); }
    __syncthreads();

    float p = 0.f;
    {
        float lg = 0.f;
        if (t < 16) {
            #pragma unroll
            for (int c = 0; c < 25; ++c) lg += s_part[t * 25 + c];
            if (lg == 0.0f) lg = -10000.0f;
            lg = lg >= 0.f ? lg : 0.01f * lg;
        }
        float mx = lg;
        mx = fmaxf(mx, __shfl_xor(mx, 1, 16));
        mx = fmaxf(mx, __shfl_xor(mx, 2, 16));
        mx = fmaxf(mx, __shfl_xor(mx, 4, 16));
        mx = fmaxf(mx, __shfl_xor(mx, 8, 16));
        const float e = __expf(lg - mx);
        float sm = e;
        sm += __shfl_xor(sm, 1, 16);
        sm += __shfl_xor(sm, 2, 16);
        sm += __shfl_xor(sm, 4, 16);
        sm += __shfl_xor(sm, 8, 16);
        p = e / sm;
        if (p == 0.0625f) p = 0.f;
    }
    __syncthreads();

    #pragma unroll
    for (int j = 0; j < 6; ++j) {
        const int i = t + 64 * j;
        const float pn = __shfl(p, i / 25, 64);
        s_pp[i] = make_float4(pn * va[j].x, pn * va[j].y, pn * va[j].z, pn * va[j].w);
    }
    if (t < 16) {
        const int i = 384 + t;
        const float pn = __shfl(p, 15, 64);
        s_pp[i] = make_float4(pn * va[6].x, pn * va[6].y, pn * va[6].z, pn * va[6].w);
    }
    __syncthreads();

    if (t < 25) {
        float4 a = make_float4(0.f, 0.f, 0.f, 0.f);
        #pragma unroll
        for (int n = 0; n < 16; ++n) {
            const float4 x = s_pp[n * 25 + t];
            a.x += x.x; a.y += x.y; a.z += x.z; a.w += x.w;
        }
        ((float4*)comb)[(size_t)be * 50 + half * 25 + t] = a;
    }
}

// ---------------------------------------------------------------------------
// gather: one block per (b,s)
// ---------------------------------------------------------------------------
__global__ __launch_bounds__(64) void gather_kernel(
    const float* __restrict__ comb, const int* __restrict__ rk, float* __restrict__ out)
{
    const int bs = blockIdx.x;
    const int b  = bs >> 8;
    const int t  = threadIdx.x;
    const int r  = rk[bs];
    float* o = out + (size_t)bs * (2 * DD);
    if (r < 0) {
        for (int d = t; d < 2 * DD; d += 64) o[d] = 0.f;
    } else {
        const float* src = comb + (size_t)(b * EE + r) * (2 * DD);
        for (int d = t; d < 2 * DD; d += 64) o[d] = src[d];
    }
}

extern "C" void kernel_launch(void* const* d_in, const int* in_sizes, int n_in,
                              void* d_out, int out_size, void* d_ws, size_t ws_size,
                              hipStream_t stream)
{
    const int*   ent = (const int*)d_in[0];
    const float* q   = (const float*)d_in[1];
    const float* k1  = (const float*)d_in[2];
    const float* v1  = (const float*)d_in[3];
    const float* k2  = (const float*)d_in[4];
    const float* v2  = (const float*)d_in[5];
    const float* Wq2 = (const float*)d_in[6];
    const float* bq2 = (const float*)d_in[7];
    const float* Wk2 = (const float*)d_in[8];
    const float* Wq1 = (const float*)d_in[9];
    const float* bq1 = (const float*)d_in[10];
    const float* Wk1 = (const float*)d_in[11];
    float* out = (float*)d_out;

    float* ws   = (float*)d_ws;
    float* qk2  = ws;                          // [0, 1024)
    float* qk1  = ws + 1024;                   // [1024, 2048)
    int*   rk   = (int*)(ws + 2048);           // [2048, 4096) as ints
    float* comb = ws + 4096;                   // [4096, 4096+409600)
    float* c2   = ws + 4096 + 409600;          // per-b chunks of 409600 floats

    const size_t fixed = 4096 + 409600;        // floats
    const size_t perb  = (size_t)EE * NN1 * DD; // 409600 floats per batch
    size_t wsf = ws_size / sizeof(float);
    int kb = (wsf > fixed) ? (int)((wsf - fixed) / perb) : 1;
    if (kb < 1) kb = 1;
    if (kb > BB) kb = BB;

    prep_kernel<<<24, 256, 0, stream>>>(q, ent, Wq2, bq2, Wk2, Wq1, bq1, Wk1, qk2, qk1, rk);
    for (int b0 = 0; b0 < BB; b0 += kb) {
        const int nb = (BB - b0 < kb) ? (BB - b0) : kb;
        const int nunits = nb * EE * NN1;      // single-tile units
        const int grid = nunits < 4096 ? nunits : 4096;
        dk2_kernel<<<grid, 64, 0, stream>>>(k2, v2, qk2, c2, b0, nunits);
        dk1_kernel<<<nb * EE * 2, 64, 0, stream>>>(k1, v1, c2, qk1, comb, b0);
    }
    gather_kernel<<<BB * SS, 64, 0, stream>>>(comb, rk, out);
}